// Round 11
// baseline (4007.640 us; speedup 1.0000x reference)
//
#include <hip/hip_runtime.h>
#include <hip/hip_bf16.h>
#include <math.h>

// ---- problem constants (from reference) ----
#define PATCH   16
#define HIMG    384
#define WIMG    384
#define DMODEL  1024
#define NLAYERS 24
#define DI      2048
#define DSTATE  16
#define DTR     64
#define DC      4
#define LN_EPS  1e-5f
#define BATCH   2
#define GRIDTOK 24                 // 384/16
#define LTOK    (GRIDTOK*GRIDTOK)  // 576
#define NTOK    (BATCH*LTOK)       // 1152
#define KPATCH  (3*PATCH*PATCH)    // 768
#define NCH     16                 // scan chunks
#define LC      (LTOK/NCH)         // 36 steps per chunk
#define PSTRIDE ((size_t)NTOK * 2 * DI)   // split-K partial stride (floats)
#define XP_SK   16                 // xproj split-K

typedef __attribute__((ext_vector_type(8))) short short8;
typedef __attribute__((ext_vector_type(4))) float f32x4;

__device__ __forceinline__ float sigmoidf_(float v) { return 1.f / (1.f + __expf(-v)); }
__device__ __forceinline__ unsigned short f2bf(float f) {
    __hip_bfloat16 h = __float2bfloat16(f);   // RNE
    return *(unsigned short*)&h;
}

// ---- bijective XCD-chunk swizzle (m204 form) ----
__device__ __forceinline__ int xcd_swizzle(int orig, int nwg) {
    const int q = nwg >> 3, r = nwg & 7;
    const int xcd = orig & 7, idx = orig >> 3;
    return (xcd < r ? xcd * (q + 1) : r * (q + 1) + (xcd - r) * q) + idx;
}
__device__ __forceinline__ void swz_xyz(int& bx, int& by, int& bz) {
    const int gx = gridDim.x, gy = gridDim.y;
    const int nwg = gx * gy * gridDim.z;
    const int orig = blockIdx.x + gx * (blockIdx.y + gy * blockIdx.z);
    const int id = xcd_swizzle(orig, nwg);
    bx = id % gx;
    const int rest = id / gx;
    by = rest % gy;
    bz = rest / gy;
}

// ---------------- fp32 -> bf16 bulk converter (SMALL weights only) ----------------
__global__ void f2bf_kernel(const float* __restrict__ in, unsigned short* __restrict__ out, int n4) {
    for (int i = blockIdx.x * blockDim.x + threadIdx.x; i < n4; i += gridDim.x * blockDim.x) {
        const float4 v = ((const float4*)in)[i];
        ushort4 o;
        o.x = f2bf(v.x); o.y = f2bf(v.y); o.z = f2bf(v.z); o.w = f2bf(v.w);
        ((ushort4*)out)[i] = o;
    }
}

// ---------------- im2col (bf16 out) ----------------
__global__ void im2col_kernel(const float* __restrict__ x, unsigned short* __restrict__ xcol) {
    int idx = blockIdx.x * blockDim.x + threadIdx.x;
    if (idx >= NTOK * KPATCH) return;
    int t = idx / KPATCH, k = idx % KPATCH;
    int b = t / LTOK, hw = t % LTOK;
    int h = hw / GRIDTOK, w = hw % GRIDTOK;
    int c = k / (PATCH*PATCH), r = k % (PATCH*PATCH);
    int i = r / PATCH, j = r % PATCH;
    xcol[idx] = f2bf(x[(((size_t)(b*3 + c)*HIMG) + h*PATCH + i)*WIMG + w*PATCH + j]);
}

// ---------------- LayerNorm (layer 0 only) ----------------
__global__ __launch_bounds__(256) void layernorm_kernel(
        const float* __restrict__ x, const float* __restrict__ g,
        const float* __restrict__ b, unsigned short* __restrict__ u) {
    const int t = blockIdx.x;
    const int tid = threadIdx.x;
    const float4 xv = ((const float4*)(x + (size_t)t * DMODEL))[tid];
    float s = xv.x + xv.y + xv.z + xv.w;
    float q = xv.x*xv.x + xv.y*xv.y + xv.z*xv.z + xv.w*xv.w;
    #pragma unroll
    for (int off = 32; off >= 1; off >>= 1) {
        s += __shfl_xor(s, off);
        q += __shfl_xor(q, off);
    }
    __shared__ float red[8];
    if ((tid & 63) == 0) { red[tid >> 6] = s; red[4 + (tid >> 6)] = q; }
    __syncthreads();
    s = red[0] + red[1] + red[2] + red[3];
    q = red[4] + red[5] + red[6] + red[7];
    const float mu   = s * (1.f / DMODEL);
    const float var  = q * (1.f / DMODEL) - mu * mu;
    const float rstd = rsqrtf(var + LN_EPS);
    const float4 gv = ((const float4*)g)[tid];
    const float4 bv = ((const float4*)b)[tid];
    ushort4 o;
    o.x = f2bf((xv.x - mu) * rstd * gv.x + bv.x);
    o.y = f2bf((xv.y - mu) * rstd * gv.y + bv.y);
    o.z = f2bf((xv.z - mu) * rstd * gv.z + bv.z);
    o.w = f2bf((xv.w - mu) * rstd * gv.w + bv.w);
    ((ushort4*)(u + (size_t)t * DMODEL))[tid] = o;
}

// ================ bf16 MFMA GEMM (fp32-B, convert in staging): ================
// C[M,N] = A_bf16[M,K] * B_f32[N,K]^T.  128x128 tile, BK=64, 4 waves of 64x64.
// XOR-swizzled LDS. grid.z = split-K: partials at C + z*M*N. XCD-swizzled blocks.
__global__ __launch_bounds__(256) void gemm_mfma_bt(
        const unsigned short* __restrict__ A, int lda,
        const float* __restrict__ B, int ldb,
        float* __restrict__ C, int M, int N, int Ksub) {
    __shared__ unsigned short As[128 * 64];
    __shared__ unsigned short Bs[128 * 64];
    int bx, by, bz;
    swz_xyz(bx, by, bz);
    const int tid = threadIdx.x;
    const int m0 = bx * 128;
    const int n0 = by * 128;
    const int koff = bz * Ksub;
    C += (size_t)bz * M * N;

    const int lane = tid & 63;
    const int wid  = tid >> 6;
    const int wm = (wid >> 1) * 64;
    const int wn = (wid & 1) * 64;
    const int fr = lane & 15;
    const int cb = lane >> 4;

    const int srow = tid >> 3;          // 0..31
    const int skc  = tid & 7;           // 0..7

    f32x4 acc[4][4];
    #pragma unroll
    for (int i = 0; i < 4; ++i)
        #pragma unroll
        for (int j = 0; j < 4; ++j) acc[i][j] = (f32x4){0.f, 0.f, 0.f, 0.f};

    uint4  areg[4];
    float4 breg[4][2];

    const int nk = Ksub / 64;
    #pragma unroll
    for (int i = 0; i < 4; ++i) {
        const int r = srow + 32 * i;
        areg[i] = *(const uint4*)(A + (size_t)(m0 + r) * lda + koff + skc * 8);
        const float* bp = B + (size_t)(n0 + r) * ldb + koff + skc * 8;
        breg[i][0] = *(const float4*)bp;
        breg[i][1] = *(const float4*)(bp + 4);
    }

    for (int ks = 0; ks < nk; ++ks) {
        __syncthreads();
        #pragma unroll
        for (int i = 0; i < 4; ++i) {
            const int r = srow + 32 * i;
            const int idx = r * 64 + ((skc ^ (r & 7)) << 3);
            *(uint4*)&As[idx] = areg[i];
            const float* bf = (const float*)&breg[i][0];
            short8 hv;
            #pragma unroll
            for (int j = 0; j < 8; ++j) hv[j] = (short)f2bf(bf[j]);
            *(short8*)&Bs[idx] = hv;
        }
        __syncthreads();
        if (ks + 1 < nk) {
            const int k1 = koff + (ks + 1) * 64;
            #pragma unroll
            for (int i = 0; i < 4; ++i) {
                const int r = srow + 32 * i;
                areg[i] = *(const uint4*)(A + (size_t)(m0 + r) * lda + k1 + skc * 8);
                const float* bp = B + (size_t)(n0 + r) * ldb + k1 + skc * 8;
                breg[i][0] = *(const float4*)bp;
                breg[i][1] = *(const float4*)(bp + 4);
            }
        }
        #pragma unroll
        for (int kk = 0; kk < 2; ++kk) {
            short8 af[4], bfr[4];
            #pragma unroll
            for (int mi = 0; mi < 4; ++mi) {
                const int row = wm + mi * 16 + fr;
                af[mi] = *(const short8*)&As[row * 64 + (((kk * 4 + cb) ^ (row & 7)) << 3)];
            }
            #pragma unroll
            for (int ni = 0; ni < 4; ++ni) {
                const int row = wn + ni * 16 + fr;
                bfr[ni] = *(const short8*)&Bs[row * 64 + (((kk * 4 + cb) ^ (row & 7)) << 3)];
            }
            #pragma unroll
            for (int mi = 0; mi < 4; ++mi)
                #pragma unroll
                for (int ni = 0; ni < 4; ++ni)
                    acc[mi][ni] = __builtin_amdgcn_mfma_f32_16x16x32_bf16(
                        af[mi], bfr[ni], acc[mi][ni], 0, 0, 0);
        }
    }

    // C/D mapping (verified): col = lane&15, row = (lane>>4)*4 + reg
    #pragma unroll
    for (int mi = 0; mi < 4; ++mi) {
        const int rbase = m0 + wm + mi * 16 + cb * 4;
        #pragma unroll
        for (int ni = 0; ni < 4; ++ni) {
            const int col = n0 + wn + ni * 16 + fr;
            #pragma unroll
            for (int j = 0; j < 4; ++j)
                C[(size_t)(rbase + j) * N + col] = acc[mi][ni][j];
        }
    }
}

// ================ bf16xbf16 MFMA GEMM (patch embed) ================
template<int EPI>
__global__ __launch_bounds__(256) void gemm_bb(
        const unsigned short* __restrict__ A, int lda,
        const unsigned short* __restrict__ B, int ldb,
        float* __restrict__ C, int M, int N, int Ksub,
        const float* __restrict__ bias, const float* __restrict__ aux) {
    __shared__ unsigned short As[128 * 64];
    __shared__ unsigned short Bs[128 * 64];
    int bx, by, bz;
    swz_xyz(bx, by, bz);
    const int tid = threadIdx.x;
    const int m0 = bx * 128;
    const int n0 = by * 128;

    const int lane = tid & 63;
    const int wid  = tid >> 6;
    const int wm = (wid >> 1) * 64;
    const int wn = (wid & 1) * 64;
    const int fr = lane & 15;
    const int cb = lane >> 4;
    const int srow = tid >> 3;
    const int skc  = tid & 7;

    f32x4 acc[4][4];
    #pragma unroll
    for (int i = 0; i < 4; ++i)
        #pragma unroll
        for (int j = 0; j < 4; ++j) acc[i][j] = (f32x4){0.f, 0.f, 0.f, 0.f};

    uint4 areg[4], breg[4];
    const int nk = Ksub / 64;
    #pragma unroll
    for (int i = 0; i < 4; ++i) {
        const int r = srow + 32 * i;
        areg[i] = *(const uint4*)(A + (size_t)(m0 + r) * lda + skc * 8);
        breg[i] = *(const uint4*)(B + (size_t)(n0 + r) * ldb + skc * 8);
    }

    for (int ks = 0; ks < nk; ++ks) {
        __syncthreads();
        #pragma unroll
        for (int i = 0; i < 4; ++i) {
            const int r = srow + 32 * i;
            const int idx = r * 64 + ((skc ^ (r & 7)) << 3);
            *(uint4*)&As[idx] = areg[i];
            *(uint4*)&Bs[idx] = breg[i];
        }
        __syncthreads();
        if (ks + 1 < nk) {
            const int k1 = (ks + 1) * 64;
            #pragma unroll
            for (int i = 0; i < 4; ++i) {
                const int r = srow + 32 * i;
                areg[i] = *(const uint4*)(A + (size_t)(m0 + r) * lda + k1 + skc * 8);
                breg[i] = *(const uint4*)(B + (size_t)(n0 + r) * ldb + k1 + skc * 8);
            }
        }
        #pragma unroll
        for (int kk = 0; kk < 2; ++kk) {
            short8 af[4], bfr[4];
            #pragma unroll
            for (int mi = 0; mi < 4; ++mi) {
                const int row = wm + mi * 16 + fr;
                af[mi] = *(const short8*)&As[row * 64 + (((kk * 4 + cb) ^ (row & 7)) << 3)];
            }
            #pragma unroll
            for (int ni = 0; ni < 4; ++ni) {
                const int row = wn + ni * 16 + fr;
                bfr[ni] = *(const short8*)&Bs[row * 64 + (((kk * 4 + cb) ^ (row & 7)) << 3)];
            }
            #pragma unroll
            for (int mi = 0; mi < 4; ++mi)
                #pragma unroll
                for (int ni = 0; ni < 4; ++ni)
                    acc[mi][ni] = __builtin_amdgcn_mfma_f32_16x16x32_bf16(
                        af[mi], bfr[ni], acc[mi][ni], 0, 0, 0);
        }
    }

    #pragma unroll
    for (int mi = 0; mi < 4; ++mi) {
        const int rbase = m0 + wm + mi * 16 + cb * 4;
        #pragma unroll
        for (int ni = 0; ni < 4; ++ni) {
            const int col = n0 + wn + ni * 16 + fr;
            #pragma unroll
            for (int j = 0; j < 4; ++j) {
                float v = acc[mi][ni][j];
                if (EPI == 2)
                    v += bias[col] + aux[(size_t)((rbase + j) % LTOK) * DMODEL + col];
                C[(size_t)(rbase + j) * N + col] = v;
            }
        }
    }
}

// ---- FUSED conv1d+silu + xproj GEMM: 64x96 tile, split-K=16 -> 288 blocks ----
// A[t,e] = silu(conv(xi-partials)) computed during staging; also written to xc.
// C[z][NTOK][96] partials; B = Wxp bf16 [96, DI].
__global__ __launch_bounds__(256) void gemm_xproj_conv(
        const float* __restrict__ xzP,        // 2 fp32 in_proj partials
        const float* __restrict__ wc,         // [DI,4]
        const float* __restrict__ bc,         // [DI]
        const unsigned short* __restrict__ B, // Wxp bf16
        float* __restrict__ C,                // dbcP partials
        float* __restrict__ xc) {             // side output [NTOK, DI]
    __shared__ unsigned short As[64 * 64];
    __shared__ unsigned short Bs[96 * 64];
    int bx, by, bz;
    swz_xyz(bx, by, bz);          // grid (18, XP_SK)
    const int tid = threadIdx.x;
    const int m0 = bx * 64;
    const int koff = by * (DI / XP_SK);   // 128
    C += (size_t)by * NTOK * 96;

    const int lane = tid & 63;
    const int wid  = tid >> 6;
    const int wm = wid * 16;
    const int fr = lane & 15;
    const int cb = lane >> 4;
    const int srow = tid >> 3;    // 0..31
    const int skc  = tid & 7;

    f32x4 acc[6];
    #pragma unroll
    for (int j = 0; j < 6; ++j) acc[j] = (f32x4){0.f, 0.f, 0.f, 0.f};

    const int nk = (DI / XP_SK) / 64;    // 2
    for (int ks = 0; ks < nk; ++ks) {
        if (ks) __syncthreads();          // previous MFMA reads done
        // ---- stage A: conv+silu for 2 rows x 8 e's each ----
        #pragma unroll
        for (int i = 0; i < 2; ++i) {
            const int r = srow + 32 * i;
            const int t = m0 + r;
            const int l = t % LTOK;
            const int e0 = koff + ks * 64 + skc * 8;
            float a[8];
            {
                const float4 b0 = *(const float4*)(bc + e0);
                const float4 b1 = *(const float4*)(bc + e0 + 4);
                a[0]=b0.x; a[1]=b0.y; a[2]=b0.z; a[3]=b0.w;
                a[4]=b1.x; a[5]=b1.y; a[6]=b1.z; a[7]=b1.w;
            }
            float4 wv[8];
            #pragma unroll
            for (int j = 0; j < 8; ++j) wv[j] = *(const float4*)(wc + (size_t)(e0 + j) * DC);
            // taps in order k=3,2,1,0 (dt_=0..3) to match original accumulation order
            #pragma unroll
            for (int dt_ = 0; dt_ < 4; ++dt_) {
                if (l >= dt_) {
                    const float* p0 = xzP + (size_t)(t - dt_) * (2*DI) + e0;
                    const float* p1 = p0 + PSTRIDE;
                    const float4 x0 = *(const float4*)p0, x1 = *(const float4*)(p0 + 4);
                    const float4 y0 = *(const float4*)p1, y1 = *(const float4*)(p1 + 4);
                    const float sx[8] = {x0.x+y0.x, x0.y+y0.y, x0.z+y0.z, x0.w+y0.w,
                                         x1.x+y1.x, x1.y+y1.y, x1.z+y1.z, x1.w+y1.w};
                    #pragma unroll
                    for (int j = 0; j < 8; ++j) {
                        const float wk = (dt_ == 0) ? wv[j].w : (dt_ == 1) ? wv[j].z
                                       : (dt_ == 2) ? wv[j].y : wv[j].x;
                        a[j] = fmaf(wk, sx[j], a[j]);
                    }
                }
            }
            short8 hv;
            float4 o0, o1;
            #pragma unroll
            for (int j = 0; j < 8; ++j) {
                const float rv = a[j] * sigmoidf_(a[j]);
                hv[j] = (short)f2bf(rv);
                if (j < 4) ((float*)&o0)[j] = rv; else ((float*)&o1)[j-4] = rv;
            }
            float* xp = xc + (size_t)t * DI + e0;
            *(float4*)xp = o0;
            *(float4*)(xp + 4) = o1;
            *(short8*)&As[r * 64 + ((skc ^ (r & 7)) << 3)] = hv;
        }
        // ---- stage B ----
        #pragma unroll
        for (int i = 0; i < 3; ++i) {
            const int idx = tid + 256 * i;   // < 768
            const int r = idx >> 3, kc = idx & 7;
            const uint4 v = *(const uint4*)(B + (size_t)r * DI + koff + ks * 64 + kc * 8);
            *(uint4*)&Bs[r * 64 + ((kc ^ (r & 7)) << 3)] = v;
        }
        __syncthreads();
        #pragma unroll
        for (int kk = 0; kk < 2; ++kk) {
            const int arow = wm + fr;
            const short8 af = *(const short8*)&As[arow * 64 + (((kk * 4 + cb) ^ (arow & 7)) << 3)];
            short8 bfr[6];
            #pragma unroll
            for (int ni = 0; ni < 6; ++ni) {
                const int row = ni * 16 + fr;
                bfr[ni] = *(const short8*)&Bs[row * 64 + (((kk * 4 + cb) ^ (row & 7)) << 3)];
            }
            #pragma unroll
            for (int ni = 0; ni < 6; ++ni)
                acc[ni] = __builtin_amdgcn_mfma_f32_16x16x32_bf16(af, bfr[ni], acc[ni], 0, 0, 0);
        }
    }

    const int rbase = m0 + wm + cb * 4;
    #pragma unroll
    for (int ni = 0; ni < 6; ++ni) {
        const int col = ni * 16 + fr;
        #pragma unroll
        for (int j = 0; j < 4; ++j)
            C[(size_t)(rbase + j) * 96 + col] = acc[ni][j];
    }
}

// ---- dt GEMM (+inline reduce16 of A): 128x64 tile, K=64 -> 288 blocks ----
// A[t,c] = sum_z dbcP[z][t*96+c] (c<64), converted bf16 in staging (same order
// as the old reduce16 -> bit-identical). C = softplus(A*Wdt^T + bias).
__global__ __launch_bounds__(256) void gemm_dt(
        const float* __restrict__ dbcP,
        const unsigned short* __restrict__ B,
        float* __restrict__ C, const float* __restrict__ bias) {
    __shared__ unsigned short As[128 * 64];
    __shared__ unsigned short Bs[64 * 64];
    int bx, by, bz;
    swz_xyz(bx, by, bz);          // grid (9, 32)
    const int tid = threadIdx.x;
    const int m0 = bx * 128;
    const int n0 = by * 64;

    const int lane = tid & 63;
    const int wid  = tid >> 6;
    const int wm = (wid >> 1) * 64;
    const int wn = (wid & 1) * 32;
    const int fr = lane & 15;
    const int cb = lane >> 4;
    const int srow = tid >> 3;
    const int skc  = tid & 7;

    #pragma unroll
    for (int i = 0; i < 4; ++i) {
        const int r = srow + 32 * i;
        const int t = m0 + r;
        const float* pb = dbcP + (size_t)t * 96 + skc * 8;
        float s[8] = {0.f,0.f,0.f,0.f,0.f,0.f,0.f,0.f};
        for (int z = 0; z < XP_SK; ++z) {
            const float4 v0 = *(const float4*)(pb + (size_t)z * NTOK * 96);
            const float4 v1 = *(const float4*)(pb + (size_t)z * NTOK * 96 + 4);
            s[0]+=v0.x; s[1]+=v0.y; s[2]+=v0.z; s[3]+=v0.w;
            s[4]+=v1.x; s[5]+=v1.y; s[6]+=v1.z; s[7]+=v1.w;
        }
        short8 hv;
        #pragma unroll
        for (int j = 0; j < 8; ++j) hv[j] = (short)f2bf(s[j]);
        *(short8*)&As[r * 64 + ((skc ^ (r & 7)) << 3)] = hv;
    }
    #pragma unroll
    for (int i = 0; i < 2; ++i) {
        const int r = srow + 32 * i;
        const uint4 v = *(const uint4*)(B + (size_t)(n0 + r) * 64 + skc * 8);
        *(uint4*)&Bs[r * 64 + ((skc ^ (r & 7)) << 3)] = v;
    }
    __syncthreads();

    f32x4 acc[4][2];
    #pragma unroll
    for (int i = 0; i < 4; ++i)
        #pragma unroll
        for (int j = 0; j < 2; ++j) acc[i][j] = (f32x4){0.f, 0.f, 0.f, 0.f};

    #pragma unroll
    for (int kk = 0; kk < 2; ++kk) {
        short8 af[4], bfr[2];
        #pragma unroll
        for (int mi = 0; mi < 4; ++mi) {
            const int row = wm + mi * 16 + fr;
            af[mi] = *(const short8*)&As[row * 64 + (((kk * 4 + cb) ^ (row & 7)) << 3)];
        }
        #pragma unroll
        for (int ni = 0; ni < 2; ++ni) {
            const int row = wn + ni * 16 + fr;
            bfr[ni] = *(const short8*)&Bs[row * 64 + (((kk * 4 + cb) ^ (row & 7)) << 3)];
        }
        #pragma unroll
        for (int mi = 0; mi < 4; ++mi)
            #pragma unroll
            for (int ni = 0; ni < 2; ++ni)
                acc[mi][ni] = __builtin_amdgcn_mfma_f32_16x16x32_bf16(
                    af[mi], bfr[ni], acc[mi][ni], 0, 0, 0);
    }

    #pragma unroll
    for (int mi = 0; mi < 4; ++mi) {
        const int rbase = m0 + wm + mi * 16 + cb * 4;
        #pragma unroll
        for (int ni = 0; ni < 2; ++ni) {
            const int col = n0 + wn + ni * 16 + fr;
            #pragma unroll
            for (int j = 0; j < 4; ++j) {
                float v = acc[mi][ni][j] + bias[col];
                v = (v > 20.f) ? v : log1pf(__expf(v));
                C[(size_t)(rbase + j) * DI + col] = v;
            }
        }
    }
}

// ================= chunked parallel selective scan (B/C reduced from partials) =================
__global__ __launch_bounds__(256) void scan_pass1(
        const float* __restrict__ dt, const float* __restrict__ xc,
        const float* __restrict__ dbcP, const float* __restrict__ Alog,
        float* __restrict__ Fst, float* __restrict__ sdt) {
    const int tid = threadIdx.x;
    const int e  = blockIdx.x * 256 + tid;
    const int c  = blockIdx.y;
    const int b  = blockIdx.z;
    const int l0 = c * LC;
    const size_t tb = (size_t)b * LTOK + l0;

    __shared__ float Bs[LC][16];
    for (int idx = tid; idx < LC * 16; idx += 256) {
        const int row = idx >> 4, s = idx & 15;
        float v = 0.f;
        const float* p = dbcP + (tb + row) * 96 + 64 + s;
        #pragma unroll
        for (int z = 0; z < XP_SK; ++z) v += p[(size_t)z * NTOK * 96];
        Bs[row][s] = v;
    }

    float Aval[DSTATE];
    {
        const float* ap = Alog + (size_t)e * DSTATE;
        #pragma unroll
        for (int s = 0; s < DSTATE; ++s) Aval[s] = -__expf(ap[s]);
    }
    __syncthreads();

    const float* dtp = dt + tb * DI + e;
    const float* xcp = xc + tb * DI + e;
    float h[DSTATE];
    #pragma unroll
    for (int s = 0; s < DSTATE; ++s) h[s] = 0.f;
    float sum_dt = 0.f;

    float dtv = dtp[0], xcv = xcp[0];
    for (int l = 0; l < LC; ++l) {
        float dtn = 0.f, xcn = 0.f;
        if (l + 1 < LC) { dtn = dtp[(size_t)(l+1) * DI]; xcn = xcp[(size_t)(l+1) * DI]; }
        sum_dt += dtv;
        const float dx = dtv * xcv;
        const float4* brow = (const float4*)&Bs[l][0];
        const float4 b0 = brow[0], b1 = brow[1], b2 = brow[2], b3 = brow[3];
        const float bb[16] = {b0.x,b0.y,b0.z,b0.w, b1.x,b1.y,b1.z,b1.w,
                              b2.x,b2.y,b2.z,b2.w, b3.x,b3.y,b3.z,b3.w};
        #pragma unroll
        for (int s = 0; s < DSTATE; ++s)
            h[s] = fmaf(__expf(dtv * Aval[s]), h[s], dx * bb[s]);
        dtv = dtn; xcv = xcn;
    }

    float4* Fp = (float4*)(Fst + ((((size_t)b * NCH + c) * DI) + e) * DSTATE);
    #pragma unroll
    for (int q = 0; q < 4; ++q)
        Fp[q] = make_float4(h[q*4+0], h[q*4+1], h[q*4+2], h[q*4+3]);
    sdt[((size_t)b * NCH + c) * DI + e] = sum_dt;
}

__global__ __launch_bounds__(256) void scan_pass3(
        const float* __restrict__ dt, const float* __restrict__ xc,
        const float* __restrict__ dbcP, const float* __restrict__ xzP,
        const float* __restrict__ Alog, const float* __restrict__ Dp,
        const float* __restrict__ Fst, const float* __restrict__ sdt,
        unsigned short* __restrict__ y) {
    const int tid = threadIdx.x;
    const int e  = blockIdx.x * 256 + tid;
    const int c  = blockIdx.y;
    const int b  = blockIdx.z;
    const int l0 = c * LC;
    const size_t tb = (size_t)b * LTOK + l0;

    __shared__ float BCs[LC][32];
    for (int idx = tid; idx < LC * 32; idx += 256) {
        const int row = idx >> 5, col = idx & 31;
        float v = 0.f;
        const float* p = dbcP + (tb + row) * 96 + 64 + col;
        #pragma unroll
        for (int z = 0; z < XP_SK; ++z) v += p[(size_t)z * NTOK * 96];
        BCs[row][col] = v;
    }

    float Aval[DSTATE];
    {
        const float* ap = Alog + (size_t)e * DSTATE;
        #pragma unroll
        for (int s = 0; s < DSTATE; ++s) Aval[s] = -__expf(ap[s]);
    }
    const float Dv = Dp[e];

    float h[DSTATE];
    #pragma unroll
    for (int s = 0; s < DSTATE; ++s) h[s] = 0.f;
    for (int c2 = 0; c2 < c; ++c2) {
        const size_t base = ((size_t)b * NCH + c2) * DI + e;
        const float sd = sdt[base];
        const float4* Fp = (const float4*)(Fst + base * DSTATE);
        const float4 f0 = Fp[0], f1 = Fp[1], f2 = Fp[2], f3 = Fp[3];
        const float ff[16] = {f0.x,f0.y,f0.z,f0.w, f1.x,f1.y,f1.z,f1.w,
                              f2.x,f2.y,f2.z,f2.w, f3.x,f3.y,f3.z,f3.w};
        #pragma unroll
        for (int s = 0; s < DSTATE; ++s)
            h[s] = fmaf(__expf(Aval[s] * sd), h[s], ff[s]);
    }
    __syncthreads();

    const float* dtp = dt + tb * DI + e;
    const float* xcp = xc + tb * DI + e;
    const float* zp0 = xzP + tb * (2*DI) + DI + e;
    const float* zp1 = zp0 + PSTRIDE;
    unsigned short* yp = y + tb * DI + e;

    float dtv = dtp[0], xcv = xcp[0], zv = zp0[0] + zp1[0];
    for (int l = 0; l < LC; ++l) {
        float dtn = 0.f, xcn = 0.f, zn = 0.f;
        if (l + 1 < LC) {
            dtn = dtp[(size_t)(l+1) * DI];
            xcn = xcp[(size_t)(l+1) * DI];
            zn  = zp0[(size_t)(l+1) * (2*DI)] + zp1[(size_t)(l+1) * (2*DI)];
        }
        const float dx = dtv * xcv;
        const float4* brow = (const float4*)&BCs[l][0];
        const float4 b0 = brow[0], b1 = brow[1], b2 = brow[2], b3 = brow[3];
        const float4 c0 = brow[4], c1 = brow[5], c2 = brow[6], c3 = brow[7];
        const float bb[16] = {b0.x,b0.y,b0.z,b0.w, b1.x,b1.y,b1.z,b1.w,
                              b2.x,b2.y,b2.z,b2.w, b3.x,b3.y,b3.z,b3.w};
        const float cc[16] = {c0.x,c0.y,c0.z,c0.w, c1.x,c1.y,c1.z,c1.w,
                              c2.x,c2.y,c2.z,c2.w, c3.x,c3.y,c3.z,c3.w};
        float yv = 0.f;
        #pragma unroll
        for (int s = 0; s < DSTATE; ++s) {
            h[s] = fmaf(__expf(dtv * Aval[s]), h[s], dx * bb[s]);
            yv = fmaf(h[s], cc[s], yv);
        }
        yp[(size_t)l * DI] = f2bf((yv + Dv * xcv) * (zv * sigmoidf_(zv)));
        dtv = dtn; xcv = xcn; zv = zn;
    }
}

// ---- fused: tok += sum8(partials); u = LN(tok) (next layer) ----
template<bool DO_LN>
__global__ __launch_bounds__(256) void reduce8_ln_kernel(
        const float* __restrict__ part, float* __restrict__ tok,
        const float* __restrict__ g, const float* __restrict__ b,
        unsigned short* __restrict__ u) {
    const int t = blockIdx.x;
    const int tid = threadIdx.x;
    const int n4 = NTOK * DMODEL / 4;
    const int i = t * 256 + tid;
    float4 tv = ((float4*)tok)[i];
    #pragma unroll
    for (int z = 0; z < 8; ++z) {
        const float4 p = ((const float4*)part)[(size_t)z * n4 + i];
        tv.x += p.x; tv.y += p.y; tv.z += p.z; tv.w += p.w;
    }
    ((float4*)tok)[i] = tv;
    if (DO_LN) {
        float s = tv.x + tv.y + tv.z + tv.w;
        float q = tv.x*tv.x + tv.y*tv.y + tv.z*tv.z + tv.w*tv.w;
        #pragma unroll
        for (int off = 32; off >= 1; off >>= 1) {
            s += __shfl_xor(s, off);
            q += __shfl_xor(q, off);
        }
        __shared__ float red[8];
        if ((tid & 63) == 0) { red[tid >> 6] = s; red[4 + (tid >> 6)] = q; }
        __syncthreads();
        s = red[0] + red[1] + red[2] + red[3];
        q = red[4] + red[5] + red[6] + red[7];
        const float mu   = s * (1.f / DMODEL);
        const float var  = q * (1.f / DMODEL) - mu * mu;
        const float rstd = rsqrtf(var + LN_EPS);
        const float4 gv = ((const float4*)g)[tid];
        const float4 bv = ((const float4*)b)[tid];
        ushort4 o;
        o.x = f2bf((tv.x - mu) * rstd * gv.x + bv.x);
        o.y = f2bf((tv.y - mu) * rstd * gv.y + bv.y);
        o.z = f2bf((tv.z - mu) * rstd * gv.z + bv.z);
        o.w = f2bf((tv.w - mu) * rstd * gv.w + bv.w);
        ((ushort4*)(u + (size_t)t * DMODEL))[tid] = o;
    }
}

extern "C" void kernel_launch(void* const* d_in, const int* in_sizes, int n_in,
                              void* d_out, int out_size, void* d_ws, size_t ws_size,
                              hipStream_t stream) {
    const float* x       = (const float*)d_in[0];
    const float* patch_w = (const float*)d_in[1];
    const float* patch_b = (const float*)d_in[2];
    const float* pos     = (const float*)d_in[3];
    const float* ln_g    = (const float*)d_in[4];
    const float* ln_b    = (const float*)d_in[5];
    const float* in_w    = (const float*)d_in[6];
    const float* conv_w  = (const float*)d_in[7];
    const float* conv_b  = (const float*)d_in[8];
    const float* xproj_w = (const float*)d_in[9];
    const float* dt_w    = (const float*)d_in[10];
    const float* dt_b    = (const float*)d_in[11];
    const float* A_log   = (const float*)d_in[12];
    const float* D_par   = (const float*)d_in[13];
    const float* out_w   = (const float*)d_in[14];

    float* tok = (float*)d_out;                     // residual stream [1152,1024] fp32
    float* ws  = (float*)d_ws;
    float* xzP  = ws;  ws += 2 * PSTRIDE;             // 2 in_proj partials / 8 out_proj partials
    float* xc   = ws;  ws += (size_t)NTOK * DI;
    float* dbcP = ws;  ws += (size_t)XP_SK * NTOK * 96;
    float* dtb  = ws;  ws += (size_t)NTOK * DI;
    float* Fst  = ws;  ws += (size_t)BATCH * NCH * DI * DSTATE;
    float* sdt  = ws;  ws += (size_t)BATCH * NCH * DI;
    unsigned short* us = (unsigned short*)ws;
    unsigned short* Xcol_bf  = us; us += (size_t)NTOK * KPATCH;
    unsigned short* u_bf     = us; us += (size_t)NTOK * DMODEL;
    unsigned short* yb_bf    = us; us += (size_t)NTOK * DI;
    unsigned short* wxpb  = us; us += (size_t)NLAYERS * 96 * DI;
    unsigned short* wdtb  = us; us += (size_t)NLAYERS * DI * DTR;
    unsigned short* wpb   = us; us += (size_t)DMODEL * KPATCH;

    // ---- one-time small-weight converts ----
    f2bf_kernel<<<1024, 256, 0, stream>>>(xproj_w, wxpb, NLAYERS*96*DI/4);
    f2bf_kernel<<<1024, 256, 0, stream>>>(dt_w,    wdtb, NLAYERS*DI*DTR/4);
    f2bf_kernel<<<256,  256, 0, stream>>>(patch_w, wpb,  DMODEL*KPATCH/4);

    // ---- patch embed: tok = im2col(x) @ patch_w^T + patch_b + pos ----
    im2col_kernel<<<(NTOK*KPATCH + 255)/256, 256, 0, stream>>>(x, Xcol_bf);
    gemm_bb<2><<<dim3(NTOK/128, DMODEL/128), 256, 0, stream>>>(
        Xcol_bf, KPATCH, wpb, KPATCH, tok, NTOK, DMODEL, KPATCH, patch_b, pos);

    // LN for layer 0
    layernorm_kernel<<<NTOK, 256, 0, stream>>>(tok, ln_g, ln_b, u_bf);

    for (int layer = 0; layer < NLAYERS; ++layer) {
        const float* Win = in_w  + (size_t)layer * 2 * DI * DMODEL;   // fp32, staged-convert
        const float* Wo  = out_w + (size_t)layer * DMODEL * DI;       // fp32, staged-convert
        const unsigned short* Wxp = wxpb + (size_t)layer * 96 * DI;
        const unsigned short* Wdt = wdtb + (size_t)layer * DI * DTR;
        const float* Wc  = conv_w + (size_t)layer * DI * DC;
        const float* Bc  = conv_b + (size_t)layer * DI;
        const float* Bdt = dt_b   + (size_t)layer * DI;
        const float* Al  = A_log  + (size_t)layer * DI * DSTATE;
        const float* Dd  = D_par  + (size_t)layer * DI;

        // xz partials = u @ Win^T  [2][1152,4096]  (split-K=2 -> 576 blocks)
        gemm_mfma_bt<<<dim3(NTOK/128, (2*DI)/128, 2), 256, 0, stream>>>(
            u_bf, DMODEL, Win, DMODEL, xzP, NTOK, 2*DI, DMODEL/2);
        // FUSED conv+silu+xproj: dbc partials [16][1152,96]; xc side output
        gemm_xproj_conv<<<dim3(NTOK/64, XP_SK), 256, 0, stream>>>(
            xzP, Wc, Bc, Wxp, dbcP, xc);
        // dt = softplus((sum16 dbcP)[:, :64] @ Wdt^T + bdt)  (reduce fused in staging)
        gemm_dt<<<dim3(NTOK/128, DI/64), 256, 0, stream>>>(dbcP, Wdt, dtb, Bdt);
        // chunked parallel selective scan (B/C reduced from partials in staging)
        scan_pass1<<<dim3(DI/256, NCH, BATCH), 256, 0, stream>>>(
            dtb, xc, dbcP, Al, Fst, sdt);
        scan_pass3<<<dim3(DI/256, NCH, BATCH), 256, 0, stream>>>(
            dtb, xc, dbcP, xzP, Al, Dd, Fst, sdt, yb_bf);
        // out partials = yb @ Wo^T (split-K=8 -> 576 blocks) -> xzP (dead after pass3)
        gemm_mfma_bt<<<dim3(NTOK/128, DMODEL/128, 8), 256, 0, stream>>>(
            yb_bf, DI, Wo, DI, xzP, NTOK, DMODEL, DI/8);
        // tok += sum8(partials); u = LN(tok) for next layer
        if (layer < NLAYERS - 1)
            reduce8_ln_kernel<true><<<NTOK, 256, 0, stream>>>(
                xzP, tok, ln_g + (size_t)(layer+1) * DMODEL, ln_b + (size_t)(layer+1) * DMODEL, u_bf);
        else
            reduce8_ln_kernel<false><<<NTOK, 256, 0, stream>>>(
                xzP, tok, nullptr, nullptr, u_bf);
    }
}

// Round 12
// 3839.189 us; speedup vs baseline: 1.0439x; 1.0439x over previous
//
#include <hip/hip_runtime.h>
#include <hip/hip_bf16.h>
#include <math.h>

// ---- problem constants (from reference) ----
#define PATCH   16
#define HIMG    384
#define WIMG    384
#define DMODEL  1024
#define NLAYERS 24
#define DI      2048
#define DSTATE  16
#define DTR     64
#define DC      4
#define LN_EPS  1e-5f
#define BATCH   2
#define GRIDTOK 24                 // 384/16
#define LTOK    (GRIDTOK*GRIDTOK)  // 576
#define NTOK    (BATCH*LTOK)       // 1152
#define KPATCH  (3*PATCH*PATCH)    // 768
#define NCH     16                 // scan chunks
#define LC      (LTOK/NCH)         // 36 steps per chunk
#define XZPSTRIDE ((size_t)NTOK * 2 * DI)   // in_proj bf16 partial stride (elements)
#define XP_SK   16                 // xproj split-K

typedef __attribute__((ext_vector_type(8))) short short8;
typedef __attribute__((ext_vector_type(4))) float f32x4;

__device__ __forceinline__ float sigmoidf_(float v) { return 1.f / (1.f + __expf(-v)); }
__device__ __forceinline__ unsigned short f2bf(float f) {
    __hip_bfloat16 h = __float2bfloat16(f);   // RNE
    return *(unsigned short*)&h;
}
__device__ __forceinline__ float bf2f(unsigned short v) {
    unsigned int u = ((unsigned int)v) << 16;
    return __builtin_bit_cast(float, u);
}
__device__ __forceinline__ void storeC(float* p, float v) { *p = v; }
__device__ __forceinline__ void storeC(unsigned short* p, float v) { *p = f2bf(v); }

// ---- bijective XCD-chunk swizzle (m204 form) ----
__device__ __forceinline__ int xcd_swizzle(int orig, int nwg) {
    const int q = nwg >> 3, r = nwg & 7;
    const int xcd = orig & 7, idx = orig >> 3;
    return (xcd < r ? xcd * (q + 1) : r * (q + 1) + (xcd - r) * q) + idx;
}
__device__ __forceinline__ void swz_xyz(int& bx, int& by, int& bz) {
    const int gx = gridDim.x, gy = gridDim.y;
    const int nwg = gx * gy * gridDim.z;
    const int orig = blockIdx.x + gx * (blockIdx.y + gy * blockIdx.z);
    const int id = xcd_swizzle(orig, nwg);
    bx = id % gx;
    const int rest = id / gx;
    by = rest % gy;
    bz = rest / gy;
}

// ---------------- fp32 -> bf16 bulk converter (SMALL weights only) ----------------
__global__ void f2bf_kernel(const float* __restrict__ in, unsigned short* __restrict__ out, int n4) {
    for (int i = blockIdx.x * blockDim.x + threadIdx.x; i < n4; i += gridDim.x * blockDim.x) {
        const float4 v = ((const float4*)in)[i];
        ushort4 o;
        o.x = f2bf(v.x); o.y = f2bf(v.y); o.z = f2bf(v.z); o.w = f2bf(v.w);
        ((ushort4*)out)[i] = o;
    }
}

// ---------------- im2col (bf16 out) ----------------
__global__ void im2col_kernel(const float* __restrict__ x, unsigned short* __restrict__ xcol) {
    int idx = blockIdx.x * blockDim.x + threadIdx.x;
    if (idx >= NTOK * KPATCH) return;
    int t = idx / KPATCH, k = idx % KPATCH;
    int b = t / LTOK, hw = t % LTOK;
    int h = hw / GRIDTOK, w = hw % GRIDTOK;
    int c = k / (PATCH*PATCH), r = k % (PATCH*PATCH);
    int i = r / PATCH, j = r % PATCH;
    xcol[idx] = f2bf(x[(((size_t)(b*3 + c)*HIMG) + h*PATCH + i)*WIMG + w*PATCH + j]);
}

// ---------------- LayerNorm (layer 0 only) ----------------
__global__ __launch_bounds__(256) void layernorm_kernel(
        const float* __restrict__ x, const float* __restrict__ g,
        const float* __restrict__ b, unsigned short* __restrict__ u) {
    const int t = blockIdx.x;
    const int tid = threadIdx.x;
    const float4 xv = ((const float4*)(x + (size_t)t * DMODEL))[tid];
    float s = xv.x + xv.y + xv.z + xv.w;
    float q = xv.x*xv.x + xv.y*xv.y + xv.z*xv.z + xv.w*xv.w;
    #pragma unroll
    for (int off = 32; off >= 1; off >>= 1) {
        s += __shfl_xor(s, off);
        q += __shfl_xor(q, off);
    }
    __shared__ float red[8];
    if ((tid & 63) == 0) { red[tid >> 6] = s; red[4 + (tid >> 6)] = q; }
    __syncthreads();
    s = red[0] + red[1] + red[2] + red[3];
    q = red[4] + red[5] + red[6] + red[7];
    const float mu   = s * (1.f / DMODEL);
    const float var  = q * (1.f / DMODEL) - mu * mu;
    const float rstd = rsqrtf(var + LN_EPS);
    const float4 gv = ((const float4*)g)[tid];
    const float4 bv = ((const float4*)b)[tid];
    ushort4 o;
    o.x = f2bf((xv.x - mu) * rstd * gv.x + bv.x);
    o.y = f2bf((xv.y - mu) * rstd * gv.y + bv.y);
    o.z = f2bf((xv.z - mu) * rstd * gv.z + bv.z);
    o.w = f2bf((xv.w - mu) * rstd * gv.w + bv.w);
    ((ushort4*)(u + (size_t)t * DMODEL))[tid] = o;
}

// ================ bf16 MFMA GEMM (fp32-B, convert in staging): ================
// C[M,N] = A_bf16[M,K] * B_f32[N,K]^T.  128x128 tile, BK=64, 4 waves of 64x64.
// XOR-swizzled LDS. grid.z = split-K: partials at C + z*M*N (OT = float or bf16).
template<typename OT>
__global__ __launch_bounds__(256) void gemm_mfma_bt(
        const unsigned short* __restrict__ A, int lda,
        const float* __restrict__ B, int ldb,
        OT* __restrict__ C, int M, int N, int Ksub) {
    __shared__ unsigned short As[128 * 64];
    __shared__ unsigned short Bs[128 * 64];
    int bx, by, bz;
    swz_xyz(bx, by, bz);
    const int tid = threadIdx.x;
    const int m0 = bx * 128;
    const int n0 = by * 128;
    const int koff = bz * Ksub;
    C += (size_t)bz * M * N;

    const int lane = tid & 63;
    const int wid  = tid >> 6;
    const int wm = (wid >> 1) * 64;
    const int wn = (wid & 1) * 64;
    const int fr = lane & 15;
    const int cb = lane >> 4;

    const int srow = tid >> 3;          // 0..31
    const int skc  = tid & 7;           // 0..7

    f32x4 acc[4][4];
    #pragma unroll
    for (int i = 0; i < 4; ++i)
        #pragma unroll
        for (int j = 0; j < 4; ++j) acc[i][j] = (f32x4){0.f, 0.f, 0.f, 0.f};

    uint4  areg[4];
    float4 breg[4][2];

    const int nk = Ksub / 64;
    #pragma unroll
    for (int i = 0; i < 4; ++i) {
        const int r = srow + 32 * i;
        areg[i] = *(const uint4*)(A + (size_t)(m0 + r) * lda + koff + skc * 8);
        const float* bp = B + (size_t)(n0 + r) * ldb + koff + skc * 8;
        breg[i][0] = *(const float4*)bp;
        breg[i][1] = *(const float4*)(bp + 4);
    }

    for (int ks = 0; ks < nk; ++ks) {
        __syncthreads();
        #pragma unroll
        for (int i = 0; i < 4; ++i) {
            const int r = srow + 32 * i;
            const int idx = r * 64 + ((skc ^ (r & 7)) << 3);
            *(uint4*)&As[idx] = areg[i];
            const float* bf = (const float*)&breg[i][0];
            short8 hv;
            #pragma unroll
            for (int j = 0; j < 8; ++j) hv[j] = (short)f2bf(bf[j]);
            *(short8*)&Bs[idx] = hv;
        }
        __syncthreads();
        if (ks + 1 < nk) {
            const int k1 = koff + (ks + 1) * 64;
            #pragma unroll
            for (int i = 0; i < 4; ++i) {
                const int r = srow + 32 * i;
                areg[i] = *(const uint4*)(A + (size_t)(m0 + r) * lda + k1 + skc * 8);
                const float* bp = B + (size_t)(n0 + r) * ldb + k1 + skc * 8;
                breg[i][0] = *(const float4*)bp;
                breg[i][1] = *(const float4*)(bp + 4);
            }
        }
        #pragma unroll
        for (int kk = 0; kk < 2; ++kk) {
            short8 af[4], bfr[4];
            #pragma unroll
            for (int mi = 0; mi < 4; ++mi) {
                const int row = wm + mi * 16 + fr;
                af[mi] = *(const short8*)&As[row * 64 + (((kk * 4 + cb) ^ (row & 7)) << 3)];
            }
            #pragma unroll
            for (int ni = 0; ni < 4; ++ni) {
                const int row = wn + ni * 16 + fr;
                bfr[ni] = *(const short8*)&Bs[row * 64 + (((kk * 4 + cb) ^ (row & 7)) << 3)];
            }
            #pragma unroll
            for (int mi = 0; mi < 4; ++mi)
                #pragma unroll
                for (int ni = 0; ni < 4; ++ni)
                    acc[mi][ni] = __builtin_amdgcn_mfma_f32_16x16x32_bf16(
                        af[mi], bfr[ni], acc[mi][ni], 0, 0, 0);
        }
    }

    // C/D mapping (verified): col = lane&15, row = (lane>>4)*4 + reg
    #pragma unroll
    for (int mi = 0; mi < 4; ++mi) {
        const int rbase = m0 + wm + mi * 16 + cb * 4;
        #pragma unroll
        for (int ni = 0; ni < 4; ++ni) {
            const int col = n0 + wn + ni * 16 + fr;
            #pragma unroll
            for (int j = 0; j < 4; ++j)
                storeC(&C[(size_t)(rbase + j) * N + col], acc[mi][ni][j]);
        }
    }
}

// ================ bf16xbf16 MFMA GEMM (patch embed) ================
template<int EPI>
__global__ __launch_bounds__(256) void gemm_bb(
        const unsigned short* __restrict__ A, int lda,
        const unsigned short* __restrict__ B, int ldb,
        float* __restrict__ C, int M, int N, int Ksub,
        const float* __restrict__ bias, const float* __restrict__ aux) {
    __shared__ unsigned short As[128 * 64];
    __shared__ unsigned short Bs[128 * 64];
    int bx, by, bz;
    swz_xyz(bx, by, bz);
    const int tid = threadIdx.x;
    const int m0 = bx * 128;
    const int n0 = by * 128;

    const int lane = tid & 63;
    const int wid  = tid >> 6;
    const int wm = (wid >> 1) * 64;
    const int wn = (wid & 1) * 64;
    const int fr = lane & 15;
    const int cb = lane >> 4;
    const int srow = tid >> 3;
    const int skc  = tid & 7;

    f32x4 acc[4][4];
    #pragma unroll
    for (int i = 0; i < 4; ++i)
        #pragma unroll
        for (int j = 0; j < 4; ++j) acc[i][j] = (f32x4){0.f, 0.f, 0.f, 0.f};

    uint4 areg[4], breg[4];
    const int nk = Ksub / 64;
    #pragma unroll
    for (int i = 0; i < 4; ++i) {
        const int r = srow + 32 * i;
        areg[i] = *(const uint4*)(A + (size_t)(m0 + r) * lda + skc * 8);
        breg[i] = *(const uint4*)(B + (size_t)(n0 + r) * ldb + skc * 8);
    }

    for (int ks = 0; ks < nk; ++ks) {
        __syncthreads();
        #pragma unroll
        for (int i = 0; i < 4; ++i) {
            const int r = srow + 32 * i;
            const int idx = r * 64 + ((skc ^ (r & 7)) << 3);
            *(uint4*)&As[idx] = areg[i];
            *(uint4*)&Bs[idx] = breg[i];
        }
        __syncthreads();
        if (ks + 1 < nk) {
            const int k1 = (ks + 1) * 64;
            #pragma unroll
            for (int i = 0; i < 4; ++i) {
                const int r = srow + 32 * i;
                areg[i] = *(const uint4*)(A + (size_t)(m0 + r) * lda + k1 + skc * 8);
                breg[i] = *(const uint4*)(B + (size_t)(n0 + r) * ldb + k1 + skc * 8);
            }
        }
        #pragma unroll
        for (int kk = 0; kk < 2; ++kk) {
            short8 af[4], bfr[4];
            #pragma unroll
            for (int mi = 0; mi < 4; ++mi) {
                const int row = wm + mi * 16 + fr;
                af[mi] = *(const short8*)&As[row * 64 + (((kk * 4 + cb) ^ (row & 7)) << 3)];
            }
            #pragma unroll
            for (int ni = 0; ni < 4; ++ni) {
                const int row = wn + ni * 16 + fr;
                bfr[ni] = *(const short8*)&Bs[row * 64 + (((kk * 4 + cb) ^ (row & 7)) << 3)];
            }
            #pragma unroll
            for (int mi = 0; mi < 4; ++mi)
                #pragma unroll
                for (int ni = 0; ni < 4; ++ni)
                    acc[mi][ni] = __builtin_amdgcn_mfma_f32_16x16x32_bf16(
                        af[mi], bfr[ni], acc[mi][ni], 0, 0, 0);
        }
    }

    #pragma unroll
    for (int mi = 0; mi < 4; ++mi) {
        const int rbase = m0 + wm + mi * 16 + cb * 4;
        #pragma unroll
        for (int ni = 0; ni < 4; ++ni) {
            const int col = n0 + wn + ni * 16 + fr;
            #pragma unroll
            for (int j = 0; j < 4; ++j) {
                float v = acc[mi][ni][j];
                if (EPI == 2)
                    v += bias[col] + aux[(size_t)((rbase + j) % LTOK) * DMODEL + col];
                C[(size_t)(rbase + j) * N + col] = v;
            }
        }
    }
}

// ---- xproj GEMM: 64x96 tile, split-K=16 -> 288 blocks ----
__global__ __launch_bounds__(256) void gemm_xproj64(
        const unsigned short* __restrict__ A,
        const unsigned short* __restrict__ B,
        float* __restrict__ C) {
    __shared__ unsigned short As[64 * 64];
    __shared__ unsigned short Bs[96 * 64];
    int bx, by, bz;
    swz_xyz(bx, by, bz);          // grid (18, XP_SK)
    const int tid = threadIdx.x;
    const int m0 = bx * 64;
    const int koff = by * (DI / XP_SK);   // 128
    C += (size_t)by * NTOK * 96;

    const int lane = tid & 63;
    const int wid  = tid >> 6;
    const int wm = wid * 16;
    const int fr = lane & 15;
    const int cb = lane >> 4;
    const int srow = tid >> 3;
    const int skc  = tid & 7;

    f32x4 acc[6];
    #pragma unroll
    for (int j = 0; j < 6; ++j) acc[j] = (f32x4){0.f, 0.f, 0.f, 0.f};

    uint4 areg[2], breg[3];
    areg[0] = *(const uint4*)(A + (size_t)(m0 + srow) * DI + koff + skc * 8);
    areg[1] = *(const uint4*)(A + (size_t)(m0 + srow + 32) * DI + koff + skc * 8);
    #pragma unroll
    for (int i = 0; i < 3; ++i) {
        const int idx = tid + 256 * i;
        breg[i] = *(const uint4*)(B + (size_t)(idx >> 3) * DI + koff + (idx & 7) * 8);
    }

    const int nk = (DI / XP_SK) / 64;    // 2
    for (int ks = 0; ks < nk; ++ks) {
        __syncthreads();
        {
            const int r0 = srow, r1 = srow + 32;
            *(uint4*)&As[r0 * 64 + ((skc ^ (r0 & 7)) << 3)] = areg[0];
            *(uint4*)&As[r1 * 64 + ((skc ^ (r1 & 7)) << 3)] = areg[1];
        }
        #pragma unroll
        for (int i = 0; i < 3; ++i) {
            const int idx = tid + 256 * i;
            const int r = idx >> 3, kc = idx & 7;
            *(uint4*)&Bs[r * 64 + ((kc ^ (r & 7)) << 3)] = breg[i];
        }
        __syncthreads();
        if (ks + 1 < nk) {
            const int k1 = koff + (ks + 1) * 64;
            areg[0] = *(const uint4*)(A + (size_t)(m0 + srow) * DI + k1 + skc * 8);
            areg[1] = *(const uint4*)(A + (size_t)(m0 + srow + 32) * DI + k1 + skc * 8);
            #pragma unroll
            for (int i = 0; i < 3; ++i) {
                const int idx = tid + 256 * i;
                breg[i] = *(const uint4*)(B + (size_t)(idx >> 3) * DI + k1 + (idx & 7) * 8);
            }
        }
        #pragma unroll
        for (int kk = 0; kk < 2; ++kk) {
            const int arow = wm + fr;
            const short8 af = *(const short8*)&As[arow * 64 + (((kk * 4 + cb) ^ (arow & 7)) << 3)];
            short8 bfr[6];
            #pragma unroll
            for (int ni = 0; ni < 6; ++ni) {
                const int row = ni * 16 + fr;
                bfr[ni] = *(const short8*)&Bs[row * 64 + (((kk * 4 + cb) ^ (row & 7)) << 3)];
            }
            #pragma unroll
            for (int ni = 0; ni < 6; ++ni)
                acc[ni] = __builtin_amdgcn_mfma_f32_16x16x32_bf16(af, bfr[ni], acc[ni], 0, 0, 0);
        }
    }

    const int rbase = m0 + wm + cb * 4;
    #pragma unroll
    for (int ni = 0; ni < 6; ++ni) {
        const int col = ni * 16 + fr;
        #pragma unroll
        for (int j = 0; j < 4; ++j)
            C[(size_t)(rbase + j) * 96 + col] = acc[ni][j];
    }
}

// ---- dt GEMM: 128x64 tile, K=64 -> grid 9x32 = 288 blocks ----
__global__ __launch_bounds__(256) void gemm_dt(
        const unsigned short* __restrict__ A,
        const unsigned short* __restrict__ B,
        float* __restrict__ C, const float* __restrict__ bias) {
    __shared__ unsigned short As[128 * 64];
    __shared__ unsigned short Bs[64 * 64];
    int bx, by, bz;
    swz_xyz(bx, by, bz);          // grid (9, 32)
    const int tid = threadIdx.x;
    const int m0 = bx * 128;
    const int n0 = by * 64;

    const int lane = tid & 63;
    const int wid  = tid >> 6;
    const int wm = (wid >> 1) * 64;
    const int wn = (wid & 1) * 32;
    const int fr = lane & 15;
    const int cb = lane >> 4;
    const int srow = tid >> 3;
    const int skc  = tid & 7;

    #pragma unroll
    for (int i = 0; i < 4; ++i) {
        const int r = srow + 32 * i;
        const uint4 v = *(const uint4*)(A + (size_t)(m0 + r) * 64 + skc * 8);
        *(uint4*)&As[r * 64 + ((skc ^ (r & 7)) << 3)] = v;
    }
    #pragma unroll
    for (int i = 0; i < 2; ++i) {
        const int r = srow + 32 * i;
        const uint4 v = *(const uint4*)(B + (size_t)(n0 + r) * 64 + skc * 8);
        *(uint4*)&Bs[r * 64 + ((skc ^ (r & 7)) << 3)] = v;
    }
    __syncthreads();

    f32x4 acc[4][2];
    #pragma unroll
    for (int i = 0; i < 4; ++i)
        #pragma unroll
        for (int j = 0; j < 2; ++j) acc[i][j] = (f32x4){0.f, 0.f, 0.f, 0.f};

    #pragma unroll
    for (int kk = 0; kk < 2; ++kk) {
        short8 af[4], bfr[2];
        #pragma unroll
        for (int mi = 0; mi < 4; ++mi) {
            const int row = wm + mi * 16 + fr;
            af[mi] = *(const short8*)&As[row * 64 + (((kk * 4 + cb) ^ (row & 7)) << 3)];
        }
        #pragma unroll
        for (int ni = 0; ni < 2; ++ni) {
            const int row = wn + ni * 16 + fr;
            bfr[ni] = *(const short8*)&Bs[row * 64 + (((kk * 4 + cb) ^ (row & 7)) << 3)];
        }
        #pragma unroll
        for (int mi = 0; mi < 4; ++mi)
            #pragma unroll
            for (int ni = 0; ni < 2; ++ni)
                acc[mi][ni] = __builtin_amdgcn_mfma_f32_16x16x32_bf16(
                    af[mi], bfr[ni], acc[mi][ni], 0, 0, 0);
    }

    #pragma unroll
    for (int mi = 0; mi < 4; ++mi) {
        const int rbase = m0 + wm + mi * 16 + cb * 4;
        #pragma unroll
        for (int ni = 0; ni < 2; ++ni) {
            const int col = n0 + wn + ni * 16 + fr;
            #pragma unroll
            for (int j = 0; j < 4; ++j) {
                float v = acc[mi][ni][j] + bias[col];
                v = (v > 20.f) ? v : log1pf(__expf(v));
                C[(size_t)(rbase + j) * DI + col] = v;
            }
        }
    }
}

// ---------------- split-K reduce (16 partials) + bf16 copy of cols 0..63 ----------------
__global__ void reduce16_kernel(const float* __restrict__ part, float* __restrict__ out,
                                unsigned short* __restrict__ out64, int n) {
    int i = blockIdx.x * blockDim.x + threadIdx.x;
    if (i >= n) return;
    float s = 0.f;
    #pragma unroll
    for (int z = 0; z < XP_SK; ++z) s += part[(size_t)z * n + i];
    out[i] = s;
    const int col = i % 96;
    if (col < 64) out64[(i / 96) * 64 + col] = f2bf(s);
}

// -------- causal depthwise conv1d (DC=4) + silu; sums 2 bf16 in_proj partials --------
__global__ void conv1d_silu_kernel(const unsigned short* __restrict__ xzPb,
                                   const float* __restrict__ wc,
                                   const float* __restrict__ bc,
                                   float* __restrict__ xc,
                                   unsigned short* __restrict__ xc_bf) {
    int idx = blockIdx.x * blockDim.x + threadIdx.x;
    if (idx >= NTOK * DI) return;
    const int t = idx >> 11;
    const int e = idx & (DI - 1);
    const int l = t % LTOK;
    const float4 w = *(const float4*)(wc + e * DC);
    const unsigned short* xp0 = xzPb + (size_t)t * (2*DI) + e;
    const unsigned short* xp1 = xp0 + XZPSTRIDE;
    float acc = bc[e] + w.w * (bf2f(xp0[0]) + bf2f(xp1[0]));
    if (l >= 1) acc += w.z * (bf2f(xp0[-(2*DI)])   + bf2f(xp1[-(2*DI)]));
    if (l >= 2) acc += w.y * (bf2f(xp0[-2*(2*DI)]) + bf2f(xp1[-2*(2*DI)]));
    if (l >= 3) acc += w.x * (bf2f(xp0[-3*(2*DI)]) + bf2f(xp1[-3*(2*DI)]));
    const float r = acc * sigmoidf_(acc);
    xc[idx] = r;
    xc_bf[idx] = f2bf(r);
}

// ================= chunked parallel selective scan (NCH=16) =================
__global__ __launch_bounds__(256) void scan_pass1(
        const float* __restrict__ dt, const float* __restrict__ xc,
        const float* __restrict__ dbc, const float* __restrict__ Alog,
        float* __restrict__ Fst, float* __restrict__ sdt) {
    const int tid = threadIdx.x;
    const int e  = blockIdx.x * 256 + tid;
    const int c  = blockIdx.y;
    const int b  = blockIdx.z;
    const int l0 = c * LC;
    const size_t tb = (size_t)b * LTOK + l0;

    __shared__ float Bs[LC][16];
    for (int idx = tid; idx < LC * 16; idx += 256) {
        const int row = idx >> 4, s = idx & 15;
        Bs[row][s] = dbc[(tb + row) * 96 + 64 + s];
    }

    float Aval[DSTATE];
    {
        const float* ap = Alog + (size_t)e * DSTATE;
        #pragma unroll
        for (int s = 0; s < DSTATE; ++s) Aval[s] = -__expf(ap[s]);
    }
    __syncthreads();

    const float* dtp = dt + tb * DI + e;
    const float* xcp = xc + tb * DI + e;
    float h[DSTATE];
    #pragma unroll
    for (int s = 0; s < DSTATE; ++s) h[s] = 0.f;
    float sum_dt = 0.f;

    float dtv = dtp[0], xcv = xcp[0];
    for (int l = 0; l < LC; ++l) {
        float dtn = 0.f, xcn = 0.f;
        if (l + 1 < LC) { dtn = dtp[(size_t)(l+1) * DI]; xcn = xcp[(size_t)(l+1) * DI]; }
        sum_dt += dtv;
        const float dx = dtv * xcv;
        const float4* brow = (const float4*)&Bs[l][0];
        const float4 b0 = brow[0], b1 = brow[1], b2 = brow[2], b3 = brow[3];
        const float bb[16] = {b0.x,b0.y,b0.z,b0.w, b1.x,b1.y,b1.z,b1.w,
                              b2.x,b2.y,b2.z,b2.w, b3.x,b3.y,b3.z,b3.w};
        #pragma unroll
        for (int s = 0; s < DSTATE; ++s)
            h[s] = fmaf(__expf(dtv * Aval[s]), h[s], dx * bb[s]);
        dtv = dtn; xcv = xcn;
    }

    float4* Fp = (float4*)(Fst + ((((size_t)b * NCH + c) * DI) + e) * DSTATE);
    #pragma unroll
    for (int q = 0; q < 4; ++q)
        Fp[q] = make_float4(h[q*4+0], h[q*4+1], h[q*4+2], h[q*4+3]);
    sdt[((size_t)b * NCH + c) * DI + e] = sum_dt;
}

__global__ __launch_bounds__(256) void scan_pass3(
        const float* __restrict__ dt, const float* __restrict__ xc,
        const float* __restrict__ dbc, const unsigned short* __restrict__ xzPb,
        const float* __restrict__ Alog, const float* __restrict__ Dp,
        const float* __restrict__ Fst, const float* __restrict__ sdt,
        unsigned short* __restrict__ y) {
    const int tid = threadIdx.x;
    const int e  = blockIdx.x * 256 + tid;
    const int c  = blockIdx.y;
    const int b  = blockIdx.z;
    const int l0 = c * LC;
    const size_t tb = (size_t)b * LTOK + l0;

    __shared__ float BCs[LC][32];
    for (int idx = tid; idx < LC * 32; idx += 256) {
        const int row = idx >> 5, col = idx & 31;
        BCs[row][col] = dbc[(tb + row) * 96 + 64 + col];
    }

    float Aval[DSTATE];
    {
        const float* ap = Alog + (size_t)e * DSTATE;
        #pragma unroll
        for (int s = 0; s < DSTATE; ++s) Aval[s] = -__expf(ap[s]);
    }
    const float Dv = Dp[e];

    float h[DSTATE];
    #pragma unroll
    for (int s = 0; s < DSTATE; ++s) h[s] = 0.f;
    for (int c2 = 0; c2 < c; ++c2) {
        const size_t base = ((size_t)b * NCH + c2) * DI + e;
        const float sd = sdt[base];
        const float4* Fp = (const float4*)(Fst + base * DSTATE);
        const float4 f0 = Fp[0], f1 = Fp[1], f2 = Fp[2], f3 = Fp[3];
        const float ff[16] = {f0.x,f0.y,f0.z,f0.w, f1.x,f1.y,f1.z,f1.w,
                              f2.x,f2.y,f2.z,f2.w, f3.x,f3.y,f3.z,f3.w};
        #pragma unroll
        for (int s = 0; s < DSTATE; ++s)
            h[s] = fmaf(__expf(Aval[s] * sd), h[s], ff[s]);
    }
    __syncthreads();

    const float* dtp = dt + tb * DI + e;
    const float* xcp = xc + tb * DI + e;
    const unsigned short* zp0 = xzPb + tb * (2*DI) + DI + e;
    const unsigned short* zp1 = zp0 + XZPSTRIDE;
    unsigned short* yp = y + tb * DI + e;

    float dtv = dtp[0], xcv = xcp[0], zv = bf2f(zp0[0]) + bf2f(zp1[0]);
    for (int l = 0; l < LC; ++l) {
        float dtn = 0.f, xcn = 0.f, zn = 0.f;
        if (l + 1 < LC) {
            dtn = dtp[(size_t)(l+1) * DI];
            xcn = xcp[(size_t)(l+1) * DI];
            zn  = bf2f(zp0[(size_t)(l+1) * (2*DI)]) + bf2f(zp1[(size_t)(l+1) * (2*DI)]);
        }
        const float dx = dtv * xcv;
        const float4* brow = (const float4*)&BCs[l][0];
        const float4 b0 = brow[0], b1 = brow[1], b2 = brow[2], b3 = brow[3];
        const float4 c0 = brow[4], c1 = brow[5], c2 = brow[6], c3 = brow[7];
        const float bb[16] = {b0.x,b0.y,b0.z,b0.w, b1.x,b1.y,b1.z,b1.w,
                              b2.x,b2.y,b2.z,b2.w, b3.x,b3.y,b3.z,b3.w};
        const float cc[16] = {c0.x,c0.y,c0.z,c0.w, c1.x,c1.y,c1.z,c1.w,
                              c2.x,c2.y,c2.z,c2.w, c3.x,c3.y,c3.z,c3.w};
        float yv = 0.f;
        #pragma unroll
        for (int s = 0; s < DSTATE; ++s) {
            h[s] = fmaf(__expf(dtv * Aval[s]), h[s], dx * bb[s]);
            yv = fmaf(h[s], cc[s], yv);
        }
        yp[(size_t)l * DI] = f2bf((yv + Dv * xcv) * (zv * sigmoidf_(zv)));
        dtv = dtn; xcv = xcn; zv = zn;
    }
}

// ---- fused: tok += sum8(bf16 partials); u = LN(tok) (next layer) ----
template<bool DO_LN>
__global__ __launch_bounds__(256) void reduce8_ln_kernel(
        const unsigned short* __restrict__ part, float* __restrict__ tok,
        const float* __restrict__ g, const float* __restrict__ b,
        unsigned short* __restrict__ u) {
    const int t = blockIdx.x;
    const int tid = threadIdx.x;
    const size_t n = (size_t)NTOK * DMODEL;
    const size_t i = (size_t)t * 1024 + tid * 4;
    float4 tv = *(float4*)(tok + i);
    #pragma unroll
    for (int z = 0; z < 8; ++z) {
        const ushort4 p = *(const ushort4*)(part + (size_t)z * n + i);
        tv.x += bf2f(p.x); tv.y += bf2f(p.y); tv.z += bf2f(p.z); tv.w += bf2f(p.w);
    }
    *(float4*)(tok + i) = tv;
    if (DO_LN) {
        float s = tv.x + tv.y + tv.z + tv.w;
        float q = tv.x*tv.x + tv.y*tv.y + tv.z*tv.z + tv.w*tv.w;
        #pragma unroll
        for (int off = 32; off >= 1; off >>= 1) {
            s += __shfl_xor(s, off);
            q += __shfl_xor(q, off);
        }
        __shared__ float red[8];
        if ((tid & 63) == 0) { red[tid >> 6] = s; red[4 + (tid >> 6)] = q; }
        __syncthreads();
        s = red[0] + red[1] + red[2] + red[3];
        q = red[4] + red[5] + red[6] + red[7];
        const float mu   = s * (1.f / DMODEL);
        const float var  = q * (1.f / DMODEL) - mu * mu;
        const float rstd = rsqrtf(var + LN_EPS);
        const float4 gv = ((const float4*)g)[tid];
        const float4 bv = ((const float4*)b)[tid];
        ushort4 o;
        o.x = f2bf((tv.x - mu) * rstd * gv.x + bv.x);
        o.y = f2bf((tv.y - mu) * rstd * gv.y + bv.y);
        o.z = f2bf((tv.z - mu) * rstd * gv.z + bv.z);
        o.w = f2bf((tv.w - mu) * rstd * gv.w + bv.w);
        ((ushort4*)(u + (size_t)t * DMODEL))[tid] = o;
    }
}

extern "C" void kernel_launch(void* const* d_in, const int* in_sizes, int n_in,
                              void* d_out, int out_size, void* d_ws, size_t ws_size,
                              hipStream_t stream) {
    const float* x       = (const float*)d_in[0];
    const float* patch_w = (const float*)d_in[1];
    const float* patch_b = (const float*)d_in[2];
    const float* pos     = (const float*)d_in[3];
    const float* ln_g    = (const float*)d_in[4];
    const float* ln_b    = (const float*)d_in[5];
    const float* in_w    = (const float*)d_in[6];
    const float* conv_w  = (const float*)d_in[7];
    const float* conv_b  = (const float*)d_in[8];
    const float* xproj_w = (const float*)d_in[9];
    const float* dt_w    = (const float*)d_in[10];
    const float* dt_b    = (const float*)d_in[11];
    const float* A_log   = (const float*)d_in[12];
    const float* D_par   = (const float*)d_in[13];
    const float* out_w   = (const float*)d_in[14];

    float* tok = (float*)d_out;                     // residual stream [1152,1024] fp32
    float* ws  = (float*)d_ws;
    float* xc   = ws;  ws += (size_t)NTOK * DI;
    float* dbcP = ws;  ws += (size_t)XP_SK * NTOK * 96;
    float* dbc  = ws;  ws += (size_t)NTOK * 96;
    float* dtb  = ws;  ws += (size_t)NTOK * DI;
    float* Fst  = ws;  ws += (size_t)BATCH * NCH * DI * DSTATE;
    float* sdt  = ws;  ws += (size_t)BATCH * NCH * DI;
    unsigned short* us = (unsigned short*)ws;
    unsigned short* xzPb     = us; us += 2 * XZPSTRIDE;                 // in_proj bf16 partials
    unsigned short* xzPo     = us; us += (size_t)8 * NTOK * DMODEL;     // out_proj bf16 partials
    unsigned short* Xcol_bf  = us; us += (size_t)NTOK * KPATCH;
    unsigned short* u_bf     = us; us += (size_t)NTOK * DMODEL;
    unsigned short* xc_bf    = us; us += (size_t)NTOK * DI;
    unsigned short* yb_bf    = us; us += (size_t)NTOK * DI;
    unsigned short* dbc64_bf = us; us += (size_t)NTOK * 64;
    unsigned short* wxpb  = us; us += (size_t)NLAYERS * 96 * DI;
    unsigned short* wdtb  = us; us += (size_t)NLAYERS * DI * DTR;
    unsigned short* wpb   = us; us += (size_t)DMODEL * KPATCH;

    // ---- one-time small-weight converts ----
    f2bf_kernel<<<1024, 256, 0, stream>>>(xproj_w, wxpb, NLAYERS*96*DI/4);
    f2bf_kernel<<<1024, 256, 0, stream>>>(dt_w,    wdtb, NLAYERS*DI*DTR/4);
    f2bf_kernel<<<256,  256, 0, stream>>>(patch_w, wpb,  DMODEL*KPATCH/4);

    // ---- patch embed: tok = im2col(x) @ patch_w^T + patch_b + pos ----
    im2col_kernel<<<(NTOK*KPATCH + 255)/256, 256, 0, stream>>>(x, Xcol_bf);
    gemm_bb<2><<<dim3(NTOK/128, DMODEL/128), 256, 0, stream>>>(
        Xcol_bf, KPATCH, wpb, KPATCH, tok, NTOK, DMODEL, KPATCH, patch_b, pos);

    // LN for layer 0
    layernorm_kernel<<<NTOK, 256, 0, stream>>>(tok, ln_g, ln_b, u_bf);

    for (int layer = 0; layer < NLAYERS; ++layer) {
        const float* Win = in_w  + (size_t)layer * 2 * DI * DMODEL;   // fp32, staged-convert
        const float* Wo  = out_w + (size_t)layer * DMODEL * DI;       // fp32, staged-convert
        const unsigned short* Wxp = wxpb + (size_t)layer * 96 * DI;
        const unsigned short* Wdt = wdtb + (size_t)layer * DI * DTR;
        const float* Wc  = conv_w + (size_t)layer * DI * DC;
        const float* Bc  = conv_b + (size_t)layer * DI;
        const float* Bdt = dt_b   + (size_t)layer * DI;
        const float* Al  = A_log  + (size_t)layer * DI * DSTATE;
        const float* Dd  = D_par  + (size_t)layer * DI;

        // xz partials (bf16) = u @ Win^T  [2][1152,4096]  (split-K=2 -> 576 blocks)
        gemm_mfma_bt<unsigned short><<<dim3(NTOK/128, (2*DI)/128, 2), 256, 0, stream>>>(
            u_bf, DMODEL, Win, DMODEL, xzPb, NTOK, 2*DI, DMODEL/2);
        // xc = silu(causal_conv(p0+p1) + bc)
        conv1d_silu_kernel<<<(NTOK*DI + 255)/256, 256, 0, stream>>>(xzPb, Wc, Bc, xc, xc_bf);
        // dbc partials = xc @ Wxp^T  [16][1152,96]  (288 blocks)
        gemm_xproj64<<<dim3(NTOK/64, XP_SK), 256, 0, stream>>>(xc_bf, Wxp, dbcP);
        reduce16_kernel<<<(NTOK*96 + 255)/256, 256, 0, stream>>>(dbcP, dbc, dbc64_bf, NTOK*96);
        // dt = softplus(dbc[:, :64] @ Wdt^T + bdt)  [1152, 2048]  (288 blocks)
        gemm_dt<<<dim3(NTOK/128, DI/64), 256, 0, stream>>>(dbc64_bf, Wdt, dtb, Bdt);
        // chunked parallel selective scan (NCH=16)
        scan_pass1<<<dim3(DI/256, NCH, BATCH), 256, 0, stream>>>(
            dtb, xc, dbc, Al, Fst, sdt);
        scan_pass3<<<dim3(DI/256, NCH, BATCH), 256, 0, stream>>>(
            dtb, xc, dbc, xzPb, Al, Dd, Fst, sdt, yb_bf);
        // out partials (bf16) = yb @ Wo^T (split-K=8 -> 576 blocks) -> xzPo
        gemm_mfma_bt<unsigned short><<<dim3(NTOK/128, DMODEL/128, 8), 256, 0, stream>>>(
            yb_bf, DI, Wo, DI, xzPo, NTOK, DMODEL, DI/8);
        // tok += sum8(bf16 partials); u = LN(tok) for next layer
        if (layer < NLAYERS - 1)
            reduce8_ln_kernel<true><<<NTOK, 256, 0, stream>>>(
                xzPo, tok, ln_g + (size_t)(layer+1) * DMODEL, ln_b + (size_t)(layer+1) * DMODEL, u_bf);
        else
            reduce8_ln_kernel<false><<<NTOK, 256, 0, stream>>>(
                xzPo, tok, nullptr, nullptr, u_bf);
    }
}